// Round 6
// baseline (119.817 us; speedup 1.0000x reference)
//
#include <hip/hip_runtime.h>

// CTC loss forward, f64 prob-domain with power-of-2 rescaling.
// v7: v5 skeleton (fwd/bwd separate blocks, 4 waves x 4 states, ghost-zone
// halo, chunked rescale) + LDS-PIPE STARVATION.
// v6 post-mortem: the ONE-per-CU LDS pipe was the real serial resource:
// 384-512 conflicted ds_read_b32 per chunk per block ~= 3400 cy/chunk
// ~= the ~145 cy/step stall seen since v1. v7 removes per-step LDS entirely:
//  (a) per-chunk 64-read burst loads each lane's label columns (ca, cb)
//      into registers cA[32]/cC[32] (compile-time indexed, unrolled);
//  (b) blank column read from GLOBAL (uniform addr -> 1 segment, L2-hot
//      from the staging DMA) -- off the LDS pipe onto the idle VMEM pipe;
//  (c) bwd's third label column cc = lab[li0+2] = lane(l+1)'s ca -> derived
//      by f32 DPP wave_shl of cA (lane-63 garbage multiplies n1=0: harmless).
// f64 op order per state is IDENTICAL to v5 -> bit-identical, absmax 0.
// Harness-cost model: dur ~= kernels + ~60us fixed (d_ws poison fill 46us +
// launch ~15us). ws layout per b (doubles, stride 1028): [0..512] alphaF,
// [513] toteF, [514..1026] betaB, [1027] toteB.

#define Bc 64
#define Tc 1024
#define Cc 128
#define Lc 256
#define Sc 513
#define BLANKc 127
#define CHUNK 32
#define NW 4
#define PADS 64
#define WSSTRIDE 1028

constexpr float EPSF = 1e-7f;

#define DPPMAXI(x, ctrl) max(x, __builtin_amdgcn_update_dpp( \
    0, x, ctrl, 0xf, 0xf, true))

__device__ __forceinline__ double dpp_wave_shr1_f64(double x) {
    // lane l <- lane l-1; lane 0 <- 0 (bound_ctrl)
    union { double d; int i[2]; } u, r;
    u.d = x;
    r.i[0] = __builtin_amdgcn_update_dpp(0, u.i[0], 0x138, 0xf, 0xf, true);
    r.i[1] = __builtin_amdgcn_update_dpp(0, u.i[1], 0x138, 0xf, 0xf, true);
    return r.d;
}
__device__ __forceinline__ double dpp_wave_shl1_f64(double x) {
    // lane l <- lane l+1; lane 63 <- 0 (bound_ctrl)
    union { double d; int i[2]; } u, r;
    u.d = x;
    r.i[0] = __builtin_amdgcn_update_dpp(0, u.i[0], 0x130, 0xf, 0xf, true);
    r.i[1] = __builtin_amdgcn_update_dpp(0, u.i[1], 0x130, 0xf, 0xf, true);
    return r.d;
}
__device__ __forceinline__ float dpp_wave_shl1_f32(float x) {
    union { float f; int i; } u, r;
    u.f = x;
    r.i = __builtin_amdgcn_update_dpp(0, u.i, 0x130, 0xf, 0xf, true);
    return r.f;
}

__global__ __launch_bounds__(256, 1) void ctc_fb_kernel(
    const int* __restrict__ y_true,        // [B, L]
    const float* __restrict__ y_pred,      // [B, T, C]
    const int* __restrict__ label_length,  // [B, 1]
    double* __restrict__ ws)
{
    const int bb = blockIdx.x;
    const int b = bb >> 1;
    const bool isF = !(bb & 1);
    const int tid = (int)threadIdx.x;
    const int wl = tid >> 6;               // wave 0..3
    const int lane = tid & 63;

    __shared__ float bufs[3][CHUNK * Cc];  // 3 x 16 KB staged y_pred rows
    __shared__ double ash[Sc];             // owned-alpha/beta exchange
    __shared__ int em[NW];                 // per-wave masked exponent max

    const int lab_len = label_length[b];
    const float* yp = y_pred + (size_t)b * Tc * Cc;
    const int* lab = y_true + b * Lc;
    double* wsb = ws + (size_t)b * WSSTRIDE;

    // ---- region geometry (starts EVEN). fwd pads BELOW owned, bwd ABOVE.
    const int start = isF ? ((wl == 0) ? 0 : (128 * wl - PADS)) : (128 * wl);
    const int own_s = 128 * wl;
    const int own_e = (wl == NW - 1) ? Sc : (128 * (wl + 1));
    const int s0 = start + 4 * lane;       // even; lane holds s0..s0+3

    // ---- per-lane static metadata ----
    const int li0 = s0 >> 1;               // label idx of state s0+1
    const int li0c = min(li0, Lc - 1);
    const int li1c = min(li0 + 1, Lc - 1);
    const int li2c = min(li0 + 2, Lc - 1);
    const int ca = lab[li0c], cb = lab[li1c], cc = lab[li2c];
    const double sm_a = (li0 > 0 && ca != BLANKc && ca != lab[li0c - 1]) ? 1.0 : 0.0;
    const double sm_b = (cb != BLANKc && cb != ca) ? 1.0 : 0.0;
    const double sm_c = (cc != BLANKc && cc != cb) ? 1.0 : 0.0;

    const int S2 = 2 * lab_len + 1;
    const bool ow0 = (s0     >= own_s) && (s0     < own_e);
    const bool ow1 = (s0 + 1 >= own_s) && (s0 + 1 < own_e);
    const bool ow2 = (s0 + 2 >= own_s) && (s0 + 2 < own_e);
    const bool ow3 = (s0 + 3 >= own_s) && (s0 + 3 < own_e);
    const int om0 = (ow0 && s0     < S2) ? -1 : 0;
    const int om1 = (ow1 && s0 + 1 < S2) ? -1 : 0;
    const int om2 = (ow2 && s0 + 2 < S2) ? -1 : 0;
    const int om3 = (ow3 && s0 + 3 < S2) ? -1 : 0;

    // ---- staging: each wave DMAs its quarter (4 KB) of a 16 KB chunk ----
    auto stage = [&](int c, float* dst) {
        const float* g = yp + (size_t)c * (CHUNK * Cc) + lane * 4;
        #pragma unroll
        for (int q = 0; q < 4; ++q) {
            const int i = wl * 4 + q;
            __builtin_amdgcn_global_load_lds(
                (const __attribute__((address_space(1))) void*)(g + i * 256),
                (__attribute__((address_space(3))) void*)(dst + i * 256),
                16, 0, 0);
        }
    };

    // ---- per-chunk column registers (compile-time indexed only) ----
    float cB[CHUNK];                       // blank col (global, uniform)
    float cA[CHUNK];                       // label col ca  (LDS gather)
    float cC[CHUNK];                       // label col cb  (LDS gather)

    auto loadcols = [&](int c, const float* rb) {
        const float* gB = yp + (size_t)c * (CHUNK * Cc) + BLANKc;
        #pragma unroll
        for (int t = 0; t < CHUNK; ++t) {
            cA[t] = rb[t * Cc + ca];
            cC[t] = rb[t * Cc + cb];
            cB[t] = gB[t * Cc];
        }
    };

    if (isF) {
        // =================== FORWARD: rows 0 .. 511 ===================
        double a0 = 0, a1 = 0, a2 = 0, a3 = 0, n3 = 0;
        int tote = 0;
        double Eb, Ea, Ec, Ob, Oa, Oc;

        auto stepE = [&]() {
            const double t3 = __fma_rn(sm_b, a1, a3 + a2);
            const double t2 = a2 + a1;
            const double t1 = __fma_rn(sm_a, n3, a1 + a0);
            const double t0 = a0 + n3;
            a3 = t3 * Ec;
            n3 = dpp_wave_shr1_f64(a3);
            a2 = t2 * Eb; a1 = t1 * Ea; a0 = t0 * Eb;
        };
        auto stepO = [&]() {
            const double t3 = __fma_rn(sm_b, a1, a3 + a2);
            const double t2 = a2 + a1;
            const double t1 = __fma_rn(sm_a, n3, a1 + a0);
            const double t0 = a0 + n3;
            a3 = t3 * Oc;
            n3 = dpp_wave_shr1_f64(a3);
            a2 = t2 * Ob; a1 = t1 * Oa; a0 = t0 * Ob;
        };
        auto dopair = [&](int r) {         // rows r (even), r+1
            Eb = (double)(cB[r] + EPSF);
            Ea = (double)(cA[r] + EPSF);
            Ec = (double)(cC[r] + EPSF);
            stepE();
            Ob = (double)(cB[r + 1] + EPSF);
            Oa = (double)(cA[r + 1] + EPSF);
            Oc = (double)(cC[r + 1] + EPSF);
            stepO();
        };
        auto syncex = [&](int sk) {
            int e =        om0 & (__double2hiint(a0) >> 20);
            e = max(e, om1 & (__double2hiint(a1) >> 20));
            e = max(e, om2 & (__double2hiint(a2) >> 20));
            e = max(e, om3 & (__double2hiint(a3) >> 20));
            e = DPPMAXI(e, 0x111); e = DPPMAXI(e, 0x112);
            e = DPPMAXI(e, 0x114); e = DPPMAXI(e, 0x118);
            e = DPPMAXI(e, 0x142); e = DPPMAXI(e, 0x143);
            if (lane == 63) em[wl] = e;
            if (ow0) ash[s0]     = a0;
            if (ow1) ash[s0 + 1] = a1;
            if (ow2) ash[s0 + 2] = a2;
            if (ow3) ash[s0 + 3] = a3;
            __syncthreads();               // barrier 1
            const int eg = max(max(em[0], em[1]), max(em[2], em[3]));
            const int sexp = min(max(2046 - eg, 1), 2045);
            const double sc = __hiloint2double(sexp << 20, 0);
            tote += 1023 - sexp;
            if (wl > 0 && lane < (PADS / 4)) {   // refresh pad from below-owner
                a0 = ash[s0];     a1 = ash[s0 + 1];
                a2 = ash[s0 + 2]; a3 = ash[s0 + 3];
            }
            a0 *= sc; a1 *= sc; a2 *= sc; a3 *= sc;
            n3 = dpp_wave_shr1_f64(a3);
            __syncthreads();               // barrier 2
            if (sk <= 15) stage(sk, bufs[sk % 3]);  // DMA after barrier
        };

        // ---- prologue ----
        stage(0, bufs[0]); stage(1, bufs[1]); stage(2, bufs[2]);
        __syncthreads();

        // chunk 0: load columns, init from row 0, steps rows 1..31
        loadcols(0, bufs[0]);
        if (wl == 0 && lane == 0) {
            a0 = (double)(cB[0] + EPSF);                         // s=0
            if (lab_len > 0) a1 = (double)(cA[0] + EPSF);        // s=1
        }
        Ob = (double)(cB[1] + EPSF);
        Oa = (double)(cA[1] + EPSF);
        Oc = (double)(cC[1] + EPSF);
        stepO();                           // lone step t=1
        #pragma unroll
        for (int p = 1; p < 16; ++p) dopair(2 * p);

        // chunks 1..15 (rows 32..511)
        for (int k = 1; k < 16; ++k) {
            syncex(k + 2);
            loadcols(k, bufs[k % 3]);
            #pragma unroll
            for (int p = 0; p < 16; ++p) dopair(2 * p);
        }
        // publish alpha_511 (pre-rescale) + toteF
        if (ow0) wsb[s0]     = a0;
        if (ow1) wsb[s0 + 1] = a1;
        if (ow2) wsb[s0 + 2] = a2;
        if (ow3) wsb[s0 + 3] = a3;
        if (tid == 0) wsb[513] = (double)tote;
    } else {
        // =================== BACKWARD: rows 1023 .. 512 ===================
        double b0 = 0, b1 = 0, b2 = 0, b3 = 0, n0 = 0, n1 = 0;
        int tote = 0;
        double Eb, Ea, Ec, Ed, Ob, Oa, Oc, Od;

        auto stepBE = [&]() {
            const double x1 = Ea * b1, x2 = Eb * b2, x3 = Ec * b3, z = Ed * n1;
            const double r0 = __fma_rn(Eb, b0, x1);
            const double r1 = __fma_rn(sm_b, x3, x1 + x2);
            const double r2 = x2 + x3;
            const double r3 = __fma_rn(sm_c, z, __fma_rn(Eb, n0, x3));
            b0 = r0; b1 = r1; b2 = r2; b3 = r3;
            n0 = dpp_wave_shl1_f64(b0);
            n1 = dpp_wave_shl1_f64(b1);
        };
        auto stepBO = [&]() {
            const double x1 = Oa * b1, x2 = Ob * b2, x3 = Oc * b3, z = Od * n1;
            const double r0 = __fma_rn(Ob, b0, x1);
            const double r1 = __fma_rn(sm_b, x3, x1 + x2);
            const double r2 = x2 + x3;
            const double r3 = __fma_rn(sm_c, z, __fma_rn(Ob, n0, x3));
            b0 = r0; b1 = r1; b2 = r2; b3 = r3;
            n0 = dpp_wave_shl1_f64(b0);
            n1 = dpp_wave_shl1_f64(b1);
        };
        auto dopairB = [&](int r) {        // rows r+1 (odd) then r (even)
            Ob = (double)(cB[r + 1] + EPSF);
            Oa = (double)(cA[r + 1] + EPSF);
            Oc = (double)(cC[r + 1] + EPSF);
            Od = (double)(dpp_wave_shl1_f32(cA[r + 1]) + EPSF);  // cc = nbr ca
            stepBO();
            Eb = (double)(cB[r] + EPSF);
            Ea = (double)(cA[r] + EPSF);
            Ec = (double)(cC[r] + EPSF);
            Ed = (double)(dpp_wave_shl1_f32(cA[r]) + EPSF);
            stepBE();
        };
        auto syncex = [&](int sk) {
            int e =        om0 & (__double2hiint(b0) >> 20);
            e = max(e, om1 & (__double2hiint(b1) >> 20));
            e = max(e, om2 & (__double2hiint(b2) >> 20));
            e = max(e, om3 & (__double2hiint(b3) >> 20));
            e = DPPMAXI(e, 0x111); e = DPPMAXI(e, 0x112);
            e = DPPMAXI(e, 0x114); e = DPPMAXI(e, 0x118);
            e = DPPMAXI(e, 0x142); e = DPPMAXI(e, 0x143);
            if (lane == 63) em[wl] = e;
            if (ow0) ash[s0]     = b0;
            if (ow1) ash[s0 + 1] = b1;
            if (ow2) ash[s0 + 2] = b2;
            if (ow3) ash[s0 + 3] = b3;
            __syncthreads();               // barrier 1
            const int eg = max(max(em[0], em[1]), max(em[2], em[3]));
            const int sexp = min(max(2046 - eg, 1), 2045);
            const double sc = __hiloint2double(sexp << 20, 0);
            tote += 1023 - sexp;
            // refresh pad above from owner; zero beyond S space
            if (s0     >= own_e) b0 = (s0     < Sc) ? ash[s0]     : 0.0;
            if (s0 + 1 >= own_e) b1 = (s0 + 1 < Sc) ? ash[s0 + 1] : 0.0;
            if (s0 + 2 >= own_e) b2 = (s0 + 2 < Sc) ? ash[s0 + 2] : 0.0;
            if (s0 + 3 >= own_e) b3 = (s0 + 3 < Sc) ? ash[s0 + 3] : 0.0;
            b0 *= sc; b1 *= sc; b2 *= sc; b3 *= sc;
            n0 = dpp_wave_shl1_f64(b0);
            n1 = dpp_wave_shl1_f64(b1);
            __syncthreads();               // barrier 2
            if (sk >= 16) stage(sk, bufs[(31 - sk) % 3]);
        };

        // ---- prologue: chunks 31,30,29 -> bufs 0,1,2 ----
        stage(31, bufs[0]); stage(30, bufs[1]); stage(29, bufs[2]);
        __syncthreads();

        // init beta_{1023}: 1 at end states {2L, 2L-1}
        {
            const int e0 = 2 * lab_len;
            const int e1 = (lab_len > 0) ? (2 * lab_len - 1) : e0;
            b0 = (s0     == e0 || s0     == e1) ? 1.0 : 0.0;
            b1 = (s0 + 1 == e0 || s0 + 1 == e1) ? 1.0 : 0.0;
            b2 = (s0 + 2 == e0 || s0 + 2 == e1) ? 1.0 : 0.0;
            b3 = (s0 + 3 == e0 || s0 + 3 == e1) ? 1.0 : 0.0;
            n0 = dpp_wave_shl1_f64(b0);
            n1 = dpp_wave_shl1_f64(b1);
        }
        // chunk 31: rows 1023..992 (odd step first per pair, rows descend)
        loadcols(31, bufs[0]);
        #pragma unroll
        for (int p = 15; p >= 0; --p) dopairB(2 * p);

        // chunks 30..16
        for (int c = 30; c >= 16; --c) {
            syncex(c - 2);
            loadcols(c, bufs[(31 - c) % 3]);
            #pragma unroll
            for (int p = 15; p >= 0; --p) dopairB(2 * p);
        }
        // publish beta_511 (pre-rescale) + toteB
        if (ow0) wsb[514 + s0]     = b0;
        if (ow1) wsb[514 + s0 + 1] = b1;
        if (ow2) wsb[514 + s0 + 2] = b2;
        if (ow3) wsb[514 + s0 + 3] = b3;
        if (tid == 0) wsb[1027] = (double)tote;
    }
}

__global__ __launch_bounds__(64) void ctc_combine(
    const int* __restrict__ label_length,
    const double* __restrict__ ws,
    float* __restrict__ out)
{
    const int b = blockIdx.x;
    const int lane = (int)threadIdx.x;
    const int lab_len = label_length[b];
    const int S2 = 2 * lab_len + 1;
    const double* wf = ws + (size_t)b * WSSTRIDE;
    const double* wb = wf + 514;

    int eP = 0;                            // max biased-exponent sum of products
    for (int s = lane; s < S2; s += 64) {
        const int ea = (__double2hiint(wf[s]) >> 20) & 0x7ff;
        const int eb = (__double2hiint(wb[s]) >> 20) & 0x7ff;
        if (ea && eb) eP = max(eP, ea + eb);
    }
    #pragma unroll
    for (int m = 1; m < 64; m <<= 1) eP = max(eP, __shfl_xor(eP, m));
    const int sh = 2046 - eP;
    int k1 = sh / 2;
    int k2 = sh - k1;
    k1 = min(max(k1, -1022), 1023);
    k2 = min(max(k2, -1022), 1023);
    const double scA = __hiloint2double((1023 + k1) << 20, 0);
    const double scB = __hiloint2double((1023 + k2) << 20, 0);
    double dot = 0.0;
    for (int s = lane; s < S2; s += 64)
        dot += (wf[s] * scA) * (wb[s] * scB);
    #pragma unroll
    for (int m = 1; m < 64; m <<= 1) dot += __shfl_xor(dot, m);
    if (lane == 0) {
        const double lt = wf[513] + wb[513] - (double)k1 - (double)k2;
        out[b] = (float)(-(log(dot) + lt * 0.6931471805599453));
    }
}

extern "C" void kernel_launch(void* const* d_in, const int* in_sizes, int n_in,
                              void* d_out, int out_size, void* d_ws, size_t ws_size,
                              hipStream_t stream) {
    const int*   y_true       = (const int*)d_in[0];
    const float* y_pred       = (const float*)d_in[1];
    const int*   label_length = (const int*)d_in[3];
    float* out = (float*)d_out;
    double* ws = (double*)d_ws;

    ctc_fb_kernel<<<2 * Bc, NW * 64, 0, stream>>>(y_true, y_pred,
                                                  label_length, ws);
    ctc_combine<<<Bc, 64, 0, stream>>>(label_length, ws, out);
}